// Round 2
// baseline (117.486 us; speedup 1.0000x reference)
//
#include <hip/hip_runtime.h>
#include <hip/hip_bf16.h>
#include <stdint.h>

// SelfBallPointQuery: B=16, C=3, N=2048, RADIUS^2=0.04, MAX_SAMPLES=64.
// For each (b,i): first 64 ascending j with |x_i - x_j|^2 < 0.04, padded with
// the first hit. Reference output dtype is int64 -> harness maps integer
// outputs to an int32 device buffer (test reads np.int32 then astype float32),
// so we write int32 index values.

#define B_DIM 16
#define N_PTS 2048
#define K_OUT 64
#define R2 0.04f
#define QPB 32            // queries per block
#define WAVES_PER_BLOCK 4
#define QPW (QPB / WAVES_PER_BLOCK)   // 8 queries per wave

__global__ __launch_bounds__(256) void ball_query_kernel(
    const float* __restrict__ pcs,   // (B, 3, N)
    int* __restrict__ out)           // (B, N, 64) int32
{
    __shared__ float xs[N_PTS * 3];  // interleaved xyz, 24 KB

    const int b     = blockIdx.x / (N_PTS / QPB);
    const int qblk  = blockIdx.x % (N_PTS / QPB);
    const int tid   = threadIdx.x;
    const int wave  = tid >> 6;
    const int lane  = tid & 63;

    // Stage cloud b into LDS: xs[j*3 + c] = pcs[b][c][j]
    const float* src = pcs + (size_t)b * 3 * N_PTS;
    for (int idx = tid; idx < 3 * N_PTS; idx += 256) {
        const int c = idx >> 11;          // idx / 2048
        const int j = idx & (N_PTS - 1);  // idx % 2048
        xs[j * 3 + c] = src[c * N_PTS + j];
    }
    __syncthreads();

    const unsigned long long lane_mask_lt = (lane == 0) ? 0ull : (~0ull >> (64 - lane));

    for (int q = 0; q < QPW; ++q) {
        const int i = qblk * QPB + wave * QPW + q;
        // broadcast read of the query point (same LDS address, all lanes)
        const float xi = xs[i * 3 + 0];
        const float yi = xs[i * 3 + 1];
        const float zi = xs[i * 3 + 2];

        const int out_base = (b * N_PTS + i) * K_OUT;

        int count = 0;
        int first = 0;
        bool have_first = false;

        #pragma unroll 4
        for (int chunk = 0; chunk < N_PTS / 64; ++chunk) {
            const int j = chunk * 64 + lane;
            const float dx = xs[j * 3 + 0] - xi;
            const float dy = xs[j * 3 + 1] - yi;
            const float dz = xs[j * 3 + 2] - zi;
            // exact numpy f32 association, no FMA contraction:
            const float d2 = __fadd_rn(__fadd_rn(__fmul_rn(dx, dx),
                                                 __fmul_rn(dy, dy)),
                                       __fmul_rn(dz, dz));
            const bool pred = d2 < R2;
            const unsigned long long mask = __ballot(pred);
            if (!have_first && mask != 0ull) {
                first = chunk * 64 + __builtin_ctzll(mask);
                have_first = true;
            }
            const int pos = count + __popcll(mask & lane_mask_lt);
            if (pred && pos < K_OUT) {
                out[out_base + pos] = j;
            }
            count += __popcll(mask);          // wave-uniform
            if (count >= K_OUT) break;        // wave-uniform branch
        }

        if (count < K_OUT) {
            const int p = count + lane;       // 64 lanes cover [count, count+63]
            if (p < K_OUT) out[out_base + p] = first;
        }
    }
}

extern "C" void kernel_launch(void* const* d_in, const int* in_sizes, int n_in,
                              void* d_out, int out_size, void* d_ws, size_t ws_size,
                              hipStream_t stream) {
    const float* pcs = (const float*)d_in[0];
    int* out = (int*)d_out;
    const int grid = B_DIM * (N_PTS / QPB);   // 1024 blocks
    ball_query_kernel<<<grid, 256, 0, stream>>>(pcs, out);
}

// Round 3
// 97.215 us; speedup vs baseline: 1.2085x; 1.2085x over previous
//
#include <hip/hip_runtime.h>
#include <hip/hip_bf16.h>
#include <stdint.h>

// SelfBallPointQuery: B=16, C=3, N=2048, RADIUS^2=0.04, MAX_SAMPLES=64.
// For each (b,i): first 64 ascending j with |x_i - x_j|^2 < 0.04, padded with
// the first hit. int64 reference output -> int32 device buffer.
//
// R3 structure: loop inversion. Each wave owns 8 queries; the chunk loop loads
// point j = chunk*64+lane from LDS ONCE and tests it against all 8 query
// points held in registers -> 8x less LDS traffic, ~8 independent VALU chains
// per LDS load (ILP hides the ~120cyc LDS latency that bound R2).

#define B_DIM 16
#define N_PTS 2048
#define K_OUT 64
#define R2 0.04f
#define QPW 8                           // queries per wave
#define WAVES_PER_BLOCK 4
#define QPB (QPW * WAVES_PER_BLOCK)     // 32 queries per block

__global__ __launch_bounds__(256) void ball_query_kernel(
    const float* __restrict__ pcs,   // (B, 3, N)
    int* __restrict__ out)           // (B, N, 64) int32
{
    __shared__ float xs[N_PTS * 3];  // interleaved xyz, 24 KB

    const int b     = blockIdx.x / (N_PTS / QPB);
    const int qblk  = blockIdx.x % (N_PTS / QPB);
    const int tid   = threadIdx.x;
    const int wave  = tid >> 6;
    const int lane  = tid & 63;

    // Stage cloud b into LDS: xs[j*3 + c] = pcs[b][c][j]
    const float* src = pcs + (size_t)b * 3 * N_PTS;
    for (int idx = tid; idx < 3 * N_PTS; idx += 256) {
        const int c = idx >> 11;          // idx / 2048
        const int j = idx & (N_PTS - 1);  // idx % 2048
        xs[j * 3 + c] = src[c * N_PTS + j];
    }
    __syncthreads();

    const int i0 = qblk * QPB + wave * QPW;    // first query of this wave

    // Query coords in registers (broadcast LDS reads, wave-uniform addr)
    float qx[QPW], qy[QPW], qz[QPW];
    int   count[QPW], first[QPW];
    bool  havef[QPW];
    #pragma unroll
    for (int q = 0; q < QPW; ++q) {
        qx[q] = xs[(i0 + q) * 3 + 0];
        qy[q] = xs[(i0 + q) * 3 + 1];
        qz[q] = xs[(i0 + q) * 3 + 2];
        count[q] = 0; first[q] = 0; havef[q] = false;
    }

    int* const outw = out + ((size_t)b * N_PTS + i0) * K_OUT;

    for (int chunk = 0; chunk < N_PTS / 64; ++chunk) {
        const int j = chunk * 64 + lane;
        const float px = xs[j * 3 + 0];
        const float py = xs[j * 3 + 1];
        const float pz = xs[j * 3 + 2];

        #pragma unroll
        for (int q = 0; q < QPW; ++q) {
            const float dx = px - qx[q];
            const float dy = py - qy[q];
            const float dz = pz - qz[q];
            // exact numpy f32 association, no FMA contraction:
            const float d2 = __fadd_rn(__fadd_rn(__fmul_rn(dx, dx),
                                                 __fmul_rn(dy, dy)),
                                       __fmul_rn(dz, dz));
            const bool pred = d2 < R2;
            const unsigned long long mask = __ballot(pred);
            if (!havef[q] && mask != 0ull) {           // wave-uniform branch
                first[q] = chunk * 64 + __builtin_ctzll(mask);
                havef[q] = true;
            }
            // prefix-popcount of mask below this lane: v_mbcnt_lo + v_mbcnt_hi
            const int before = __builtin_amdgcn_mbcnt_hi(
                (unsigned int)(mask >> 32),
                __builtin_amdgcn_mbcnt_lo((unsigned int)mask, 0u));
            const int pos = count[q] + before;
            if (pred && pos < K_OUT) {
                outw[q * K_OUT + pos] = j;
            }
            count[q] += __popcll(mask);                // wave-uniform
        }

        // wave-uniform early exit when every query is full
        int mn = count[0];
        #pragma unroll
        for (int q = 1; q < QPW; ++q) mn = min(mn, count[q]);
        if (mn >= K_OUT) break;
    }

    // pad tails with the first hit (self-distance 0 guarantees havef)
    #pragma unroll
    for (int q = 0; q < QPW; ++q) {
        const int p = count[q] + lane;
        if (p < K_OUT) outw[q * K_OUT + p] = first[q];
    }
}

extern "C" void kernel_launch(void* const* d_in, const int* in_sizes, int n_in,
                              void* d_out, int out_size, void* d_ws, size_t ws_size,
                              hipStream_t stream) {
    const float* pcs = (const float*)d_in[0];
    int* out = (int*)d_out;
    const int grid = B_DIM * (N_PTS / QPB);   // 1024 blocks
    ball_query_kernel<<<grid, 256, 0, stream>>>(pcs, out);
}

// Round 4
// 96.785 us; speedup vs baseline: 1.2139x; 1.0044x over previous
//
#include <hip/hip_runtime.h>
#include <hip/hip_bf16.h>
#include <stdint.h>

// SelfBallPointQuery: B=16, C=3, N=2048, RADIUS^2=0.04, MAX_SAMPLES=64.
// For each (b,i): first 64 ascending j with |x_i - x_j|^2 < 0.04, padded with
// the first hit. int64 reference output -> int32 device buffer.
//
// R4: (a) float4-padded LDS, one ds_read_b128 per point; (b) removed the
// early-exit break (fires ~0.1% of the time, blocked pipelining); (c) explicit
// next-chunk prefetch so the ~120cyc LDS latency overlaps the 8-query VALU
// chain. Queries-per-wave stays 8 (grid 1024 = 4 blocks/CU).

#define B_DIM 16
#define N_PTS 2048
#define K_OUT 64
#define R2 0.04f
#define QPW 8                           // queries per wave
#define WAVES_PER_BLOCK 4
#define QPB (QPW * WAVES_PER_BLOCK)     // 32 queries per block
#define NCHUNK (N_PTS / 64)             // 32

__global__ __launch_bounds__(256) void ball_query_kernel(
    const float* __restrict__ pcs,   // (B, 3, N)
    int* __restrict__ out)           // (B, N, 64) int32
{
    __shared__ float xs4[N_PTS * 4];  // float4-padded xyz_, 32 KB

    const int b     = blockIdx.x / (N_PTS / QPB);
    const int qblk  = blockIdx.x % (N_PTS / QPB);
    const int tid   = threadIdx.x;
    const int wave  = tid >> 6;
    const int lane  = tid & 63;

    // Stage cloud b: 3 coalesced global reads per point, one b128 LDS write
    const float* src = pcs + (size_t)b * 3 * N_PTS;
    for (int j = tid; j < N_PTS; j += 256) {
        float4 p;
        p.x = src[0 * N_PTS + j];
        p.y = src[1 * N_PTS + j];
        p.z = src[2 * N_PTS + j];
        p.w = 0.0f;
        *(float4*)&xs4[j * 4] = p;
    }
    __syncthreads();

    const int i0 = qblk * QPB + wave * QPW;    // first query of this wave

    float qx[QPW], qy[QPW], qz[QPW];
    int   count[QPW], first[QPW];
    bool  havef[QPW];
    #pragma unroll
    for (int q = 0; q < QPW; ++q) {
        qx[q] = xs4[(i0 + q) * 4 + 0];
        qy[q] = xs4[(i0 + q) * 4 + 1];
        qz[q] = xs4[(i0 + q) * 4 + 2];
        count[q] = 0; first[q] = 0; havef[q] = false;
    }

    int* const outw = out + ((size_t)b * N_PTS + i0) * K_OUT;

    float4 p = *(const float4*)&xs4[lane * 4];   // chunk 0 prefetch

    for (int chunk = 0; chunk < NCHUNK; ++chunk) {
        // prefetch next chunk's point while this chunk's q-loop runs
        float4 pn;
        if (chunk + 1 < NCHUNK) {
            pn = *(const float4*)&xs4[((chunk + 1) * 64 + lane) * 4];
        }
        const int j = chunk * 64 + lane;

        #pragma unroll
        for (int q = 0; q < QPW; ++q) {
            const float dx = p.x - qx[q];
            const float dy = p.y - qy[q];
            const float dz = p.z - qz[q];
            // exact numpy f32 association, no FMA contraction:
            const float d2 = __fadd_rn(__fadd_rn(__fmul_rn(dx, dx),
                                                 __fmul_rn(dy, dy)),
                                       __fmul_rn(dz, dz));
            const bool pred = d2 < R2;
            const unsigned long long mask = __ballot(pred);
            if (!havef[q] && mask != 0ull) {           // wave-uniform branch
                first[q] = chunk * 64 + __builtin_ctzll(mask);
                havef[q] = true;
            }
            const int before = __builtin_amdgcn_mbcnt_hi(
                (unsigned int)(mask >> 32),
                __builtin_amdgcn_mbcnt_lo((unsigned int)mask, 0u));
            const int pos = count[q] + before;
            if (pred && pos < K_OUT) {
                outw[q * K_OUT + pos] = j;
            }
            count[q] += __popcll(mask);                // wave-uniform
        }
        p = pn;
    }

    // pad tails with the first hit (self-distance 0 guarantees havef)
    #pragma unroll
    for (int q = 0; q < QPW; ++q) {
        const int pp = count[q] + lane;
        if (pp < K_OUT) outw[q * K_OUT + pp] = first[q];
    }
}

extern "C" void kernel_launch(void* const* d_in, const int* in_sizes, int n_in,
                              void* d_out, int out_size, void* d_ws, size_t ws_size,
                              hipStream_t stream) {
    const float* pcs = (const float*)d_in[0];
    int* out = (int*)d_out;
    const int grid = B_DIM * (N_PTS / QPB);   // 1024 blocks
    ball_query_kernel<<<grid, 256, 0, stream>>>(pcs, out);
}